// Round 14
// baseline (262.878 us; speedup 1.0000x reference)
//
#include <hip/hip_runtime.h>
#include <math.h>

#define NDIM 64

__device__ __forceinline__ unsigned bf16rne(unsigned u) {
    return (u + 0x7fffu + ((u >> 16) & 1u)) >> 16;
}

// ---------- fused nodeprep + pack ----------
__global__ void __launch_bounds__(256)
k_prep_pack(const float* __restrict__ h,
            const float* __restrict__ pw, const float* __restrict__ nw,
            unsigned short* __restrict__ h16, float2* __restrict__ s12,
            const int* __restrict__ edges, unsigned* __restrict__ pvivj,
            int* __restrict__ hist,
            int n_nodes, int n_edges, int node_blocks) {
    if ((int)blockIdx.x < node_blocks) {
        const int lane = threadIdx.x & 63;
        const int n = blockIdx.x * 4 + (threadIdx.x >> 6);
        if (n >= n_nodes) return;
        const float a = h[(size_t)n * NDIM + lane];
        const float pa = fmaxf(a, 0.f), na = pa - a;
        float t1 = pa * pw[lane]      - na * nw[lane];
        float t2 = pa * pw[64 + lane] - na * nw[64 + lane];
        #pragma unroll
        for (int m = 32; m >= 1; m >>= 1) {
            t1 += __shfl_xor(t1, m, 64);
            t2 += __shfl_xor(t2, m, 64);
        }
        h16[(size_t)n * NDIM + lane] = (unsigned short)bf16rne(__float_as_uint(a));
        if (lane == 0) s12[n] = make_float2(t1, t2);
    } else {
        const int e = ((int)blockIdx.x - node_blocks) * 256 + threadIdx.x;
        if (e >= n_edges) return;
        const int vi = __builtin_nontemporal_load(edges + (size_t)e * 8 + 1);
        const int vj = __builtin_nontemporal_load(edges + (size_t)e * 8 + 2);
        __builtin_nontemporal_store((unsigned)vi | ((unsigned)vj << 16), pvivj + e);
        atomicAdd(&hist[vj], 1);   // vj random -> low contention
    }
}

// ---------- 3-level exclusive scan ----------
__global__ void __launch_bounds__(256)
scan_blocks(int* __restrict__ data, int* __restrict__ bsum, int n) {
    __shared__ int sm[256];
    const int t = threadIdx.x;
    const int i = blockIdx.x * 256 + t;
    int v = (i < n) ? data[i] : 0;
    sm[t] = v;
    __syncthreads();
    int x = v;
    #pragma unroll
    for (int off = 1; off < 256; off <<= 1) {
        int add = (t >= off) ? sm[t - off] : 0;
        __syncthreads();
        x += add; sm[t] = x;
        __syncthreads();
    }
    if (i < n) data[i] = x - v;
    if (t == 255) bsum[blockIdx.x] = x;
}

__global__ void __launch_bounds__(256)
scan_top(int* __restrict__ bsum, int nb) {
    __shared__ int sm[256];
    const int t = threadIdx.x;
    const int chunk = (nb + 255) / 256;
    const int beg = t * chunk, end = min(beg + chunk, nb);
    int s = 0;
    for (int i = beg; i < end; ++i) s += bsum[i];
    sm[t] = s;
    __syncthreads();
    int x = s;
    #pragma unroll
    for (int off = 1; off < 256; off <<= 1) {
        int add = (t >= off) ? sm[t - off] : 0;
        __syncthreads();
        x += add; sm[t] = x;
        __syncthreads();
    }
    int run = x - s;
    for (int i = beg; i < end; ++i) { const int v = bsum[i]; bsum[i] = run; run += v; }
}

__global__ void __launch_bounds__(256)
scan_add(int* __restrict__ data, const int* __restrict__ bsum, int n, int total) {
    const int i = blockIdx.x * 256 + threadIdx.x;
    if (i < n) data[i] += bsum[blockIdx.x];
    else if (i == n) data[i] = total;
}

// ---------- k1: 2 edges/thread; vj rows hoisted; NT rec scatter; fused seg-denom ----------
__global__ void __launch_bounds__(256)
k1_fused2(const unsigned* __restrict__ pvivj,
          const unsigned short* __restrict__ h16,
          const float2* __restrict__ s12,
          const float* __restrict__ w2p, const float* __restrict__ w2n,
          float* __restrict__ denom,
          int* __restrict__ offs,           // running cursors (post-scan)
          unsigned* __restrict__ rec,       // (vi<<16) | bf16(ex)
          int n_edges) {
    const int t = blockIdx.x * 256 + threadIdx.x;
    const int lane = threadIdx.x & 63;
    const int e0 = t * 2;
    const bool valid0 = (e0 < n_edges);
    const bool valid1 = (e0 + 1 < n_edges);
    const int ee0 = valid0 ? e0 : (n_edges - 1);
    const int ee1 = valid1 ? (e0 + 1) : ee0;

    const unsigned v0 = pvivj[ee0];
    const unsigned v1 = pvivj[ee1];
    const int vi0 = (int)(v0 & 0xffffu), vj0 = (int)(v0 >> 16);
    const int vi1 = (int)(v1 & 0xffffu), vj1 = (int)(v1 >> 16);

    const uint4* hj0 = (const uint4*)(h16 + (size_t)vj0 * NDIM);
    const uint4* hj1 = (const uint4*)(h16 + (size_t)vj1 * NDIM);
    const uint4* hi0 = (const uint4*)(h16 + (size_t)vi0 * NDIM);
    const uint4* hi1 = (const uint4*)(h16 + (size_t)vi1 * NDIM);

    // hoist the RANDOM (vj) rows of both edges: 16 independent loads in flight
    uint4 B0[8], B1[8];
    #pragma unroll
    for (int q = 0; q < 8; ++q) { B0[q] = hj0[q]; B1[q] = hj1[q]; }

    float cp0 = 0.f, cn0 = 0.f, cp1 = 0.f, cn1 = 0.f;
    #pragma unroll
    for (int q = 0; q < 8; ++q) {
        const uint4 ua0 = hi0[q];          // vi side: sorted -> L1 hits
        const uint4 ua1 = hi1[q];
        const unsigned a0u[4] = {ua0.x, ua0.y, ua0.z, ua0.w};
        const unsigned a1u[4] = {ua1.x, ua1.y, ua1.z, ua1.w};
        const unsigned b0u[4] = {B0[q].x, B0[q].y, B0[q].z, B0[q].w};
        const unsigned b1u[4] = {B1[q].x, B1[q].y, B1[q].z, B1[q].w};
        #pragma unroll
        for (int k = 0; k < 4; ++k) {
            const int d = q * 8 + k * 2;
            const float w2pd = w2p[d], w2pd1 = w2p[d + 1];
            const float w2nd = w2n[d], w2nd1 = w2n[d + 1];
            {
                const float a0 = __uint_as_float(a0u[k] << 16);
                const float a1 = __uint_as_float(a0u[k] & 0xffff0000u);
                const float b0 = __uint_as_float(b0u[k] << 16);
                const float b1 = __uint_as_float(b0u[k] & 0xffff0000u);
                const float pa0 = fmaxf(a0, 0.f), na0 = pa0 - a0;
                const float pb0 = fmaxf(b0, 0.f), nb0 = pb0 - b0;
                const float pa1 = fmaxf(a1, 0.f), na1 = pa1 - a1;
                const float pb1 = fmaxf(b1, 0.f), nb1 = pb1 - b1;
                cp0 = fmaf(pa0 * pb0, w2pd,  cp0);
                cn0 = fmaf(na0 * nb0, w2nd,  cn0);
                cp0 = fmaf(pa1 * pb1, w2pd1, cp0);
                cn0 = fmaf(na1 * nb1, w2nd1, cn0);
            }
            {
                const float a0 = __uint_as_float(a1u[k] << 16);
                const float a1 = __uint_as_float(a1u[k] & 0xffff0000u);
                const float b0 = __uint_as_float(b1u[k] << 16);
                const float b1 = __uint_as_float(b1u[k] & 0xffff0000u);
                const float pa0 = fmaxf(a0, 0.f), na0 = pa0 - a0;
                const float pb0 = fmaxf(b0, 0.f), nb0 = pb0 - b0;
                const float pa1 = fmaxf(a1, 0.f), na1 = pa1 - a1;
                const float pb1 = fmaxf(b1, 0.f), nb1 = pb1 - b1;
                cp1 = fmaf(pa0 * pb0, w2pd,  cp1);
                cn1 = fmaf(na0 * nb0, w2nd,  cn1);
                cp1 = fmaf(pa1 * pb1, w2pd1, cp1);
                cn1 = fmaf(na1 * nb1, w2nd1, cn1);
            }
        }
    }
    const float2 si0 = s12[vi0], sj0 = s12[vj0];
    const float2 si1 = s12[vi1], sj1 = s12[vj1];
    const float exf0 = valid0 ? __expf(si0.x + sj0.y + cp0 - cn0) : 0.f;
    const float exf1 = valid1 ? __expf(si1.x + sj1.y + cp1 - cn1) : 0.f;

    // ---- scatter records (NT: no write-allocate) ----
    if (valid0) {
        const int pos0 = atomicAdd(&offs[vj0], 1);
        __builtin_nontemporal_store(((unsigned)vi0 << 16) | bf16rne(__float_as_uint(exf0)), rec + pos0);
    }
    if (valid1) {
        const int pos1 = atomicAdd(&offs[vj1], 1);
        __builtin_nontemporal_store(((unsigned)vi1 << 16) | bf16rne(__float_as_uint(exf1)), rec + pos1);
    }

    // ---- fused denom: segmented reduce over this wave's 128 sorted-vi edges ----
    const int k0  = valid0 ? vi0 : -1;
    const int k1v = valid1 ? vi1 : k0;
    const float x0 = exf0, x1 = exf1;
    const float tl = (k0 == k1v) ? (x0 + x1) : x1;     // tail-run partial within lane

    int prev_k1 = __shfl_up(k1v, 1, 64);
    if (lane == 0) prev_k1 = -2;

    float s = tl;
    bool  f = !(k0 == k1v && k0 == prev_k1);           // head flag for tail chain
    #pragma unroll
    for (int o = 1; o < 64; o <<= 1) {
        const float ps = __shfl_up(s, o, 64);
        const int   pf = __shfl_up((int)f, o, 64);
        if (lane >= o) {
            if (!f) s += ps;
            f = f || (pf != 0);
        }
    }
    const float s_prev = __shfl_up(s, 1, 64);

    // run ending at element0 (inside-lane boundary)
    if (k0 >= 0 && k0 != k1v) {
        float sum0 = x0;
        if (lane > 0 && prev_k1 == k0) sum0 += s_prev;
        atomicAdd(&denom[k0], sum0);
    }
    // tail run ends here iff next lane's first key differs (or last lane)
    int next_k0 = __shfl_down(k0, 1, 64);
    const bool tail_end = (lane == 63) || (next_k0 != k1v);
    if (k1v >= 0 && tail_end)
        atomicAdd(&denom[k1v], s);
}

// ---------- gmul: g16 = bf16(h16 / denom) ----------
__global__ void __launch_bounds__(256)
k_gmul(const unsigned short* __restrict__ h16, const float* __restrict__ denom,
       unsigned short* __restrict__ g16, int n_nodes) {
    const int lane = threadIdx.x & 63;
    const int n = blockIdx.x * 4 + (threadIdx.x >> 6);
    if (n >= n_nodes) return;
    const float d = denom[n];
    const float r = (d > 0.f) ? 1.f / d : 0.f;
    const float hv = __uint_as_float((unsigned)h16[(size_t)n * NDIM + lane] << 16);
    g16[(size_t)n * NDIM + lane] = (unsigned short)bf16rne(__float_as_uint(hv * r));
}

// ---------- gather: wave per node, single segment, x16 unroll ----------
__global__ void __launch_bounds__(256)
k3b_gather(const unsigned* __restrict__ rec, const int* __restrict__ offs,
           const unsigned short* __restrict__ g16,
           float* __restrict__ out, int n_nodes) {
    const int lane = threadIdx.x & 63;
    const int n = blockIdx.x * 4 + (threadIdx.x >> 6);
    if (n >= n_nodes) return;
    const int beg = (n == 0) ? 0 : offs[n - 1];
    const int end = offs[n];
    float acc = 0.f;
    int k = beg;
    for (; k + 16 <= end; k += 16) {
        unsigned r[16];
        #pragma unroll
        for (int u = 0; u < 16; ++u) r[u] = __builtin_nontemporal_load(rec + k + u);
        float v[16];
        #pragma unroll
        for (int u = 0; u < 16; ++u)
            v[u] = __uint_as_float((unsigned)g16[(size_t)(r[u] >> 16) * NDIM + lane] << 16);
        #pragma unroll
        for (int u = 0; u < 16; ++u)
            acc = fmaf(__uint_as_float(r[u] << 16), v[u], acc);
    }
    for (; k + 4 <= end; k += 4) {
        unsigned r[4];
        #pragma unroll
        for (int u = 0; u < 4; ++u) r[u] = __builtin_nontemporal_load(rec + k + u);
        #pragma unroll
        for (int u = 0; u < 4; ++u)
            acc = fmaf(__uint_as_float(r[u] << 16),
                       __uint_as_float((unsigned)g16[(size_t)(r[u] >> 16) * NDIM + lane] << 16), acc);
    }
    for (; k < end; ++k) {
        const unsigned r = __builtin_nontemporal_load(rec + k);
        acc = fmaf(__uint_as_float(r << 16),
                   __uint_as_float((unsigned)g16[(size_t)(r >> 16) * NDIM + lane] << 16), acc);
    }
    __builtin_nontemporal_store(acc, out + (size_t)n * NDIM + lane);
}

// ================= tier C fallback (small ws; fp32, proven kernels) =================
__device__ __forceinline__ float edge_term(float a, float b,
                                           float w0, float w1, float w2,
                                           float w3, float w4, float w5) {
    const float pa = fmaxf(a, 0.f), na = pa - a;
    const float pb = fmaxf(b, 0.f), nb = pb - b;
    return pa * w0 + pb * w1 + (pa * pb) * w2
         - (na * w3 + nb * w4 + (na * nb) * w5);
}

__global__ void __launch_bounds__(256)
k1_full_c(const int* __restrict__ edges, const float* __restrict__ h,
          const float* __restrict__ pw, const float* __restrict__ nw,
          float* __restrict__ ex, int* __restrict__ hist, int n_edges) {
    const int e = blockIdx.x * 256 + threadIdx.x;
    if (e >= n_edges) return;
    const int vi = edges[(size_t)e * 8 + 1];
    const int vj = edges[(size_t)e * 8 + 2];
    const float4* hi = (const float4*)(h + (size_t)vi * NDIM);
    const float4* hj = (const float4*)(h + (size_t)vj * NDIM);
    float c = 0.f;
    #pragma unroll 4
    for (int q = 0; q < 16; ++q) {
        const float4 a = hi[q];
        const float4 b = hj[q];
        const int d = q * 4;
        c += edge_term(a.x, b.x, pw[d],     pw[64 + d],     pw[128 + d],
                                 nw[d],     nw[64 + d],     nw[128 + d]);
        c += edge_term(a.y, b.y, pw[d + 1], pw[64 + d + 1], pw[128 + d + 1],
                                 nw[d + 1], nw[64 + d + 1], nw[128 + d + 1]);
        c += edge_term(a.z, b.z, pw[d + 2], pw[64 + d + 2], pw[128 + d + 2],
                                 nw[d + 2], nw[64 + d + 2], nw[128 + d + 2]);
        c += edge_term(a.w, b.w, pw[d + 3], pw[64 + d + 3], pw[128 + d + 3],
                                 nw[d + 3], nw[64 + d + 3], nw[128 + d + 3]);
    }
    ex[e] = __expf(c);
    atomicAdd(&hist[vj], 1);
}

__global__ void __launch_bounds__(256)
k2_denom_c(const int* __restrict__ edges, const float* __restrict__ ex,
           float* __restrict__ rdenom, int n_edges, int n_nodes) {
    const int n = blockIdx.x * 256 + threadIdx.x;
    if (n >= n_nodes) return;
    int lo = 0, hi = n_edges;
    while (lo < hi) { int mid = (lo + hi) >> 1; if (edges[(size_t)mid * 8 + 1] < n) lo = mid + 1; else hi = mid; }
    const int beg = lo;
    hi = n_edges;
    while (lo < hi) { int mid = (lo + hi) >> 1; if (edges[(size_t)mid * 8 + 1] < n + 1) lo = mid + 1; else hi = mid; }
    const int end = lo;
    float s = 0.f;
    for (int e = beg; e < end; ++e) s += ex[e];
    rdenom[n] = (end > beg) ? 1.f / s : 0.f;
}

__global__ void __launch_bounds__(256)
k3a_scatter_c(const int* __restrict__ edges, const float* __restrict__ ex,
              const float* __restrict__ rdenom,
              int* __restrict__ offs, int2* __restrict__ rec8, int n_edges) {
    const int e = blockIdx.x * 256 + threadIdx.x;
    if (e >= n_edges) return;
    const int vi = edges[(size_t)e * 8 + 1];
    const int vj = edges[(size_t)e * 8 + 2];
    const float attn = ex[e] * rdenom[vi];
    const int pos = atomicAdd(&offs[vj], 1);
    rec8[pos] = make_int2(vi, __float_as_int(attn));
}

__global__ void __launch_bounds__(256)
k3b_gather_c(const int2* __restrict__ rec8, const int* __restrict__ offs,
             const float* __restrict__ h, float* __restrict__ out, int n_nodes) {
    const int lane = threadIdx.x & 63;
    const int n = blockIdx.x * 4 + (threadIdx.x >> 6);
    if (n >= n_nodes) return;
    const int beg = (n == 0) ? 0 : offs[n - 1];
    const int end = offs[n];
    float acc = 0.f;
    for (int k = beg; k < end; ++k) {
        const int2 r = rec8[k];
        acc = fmaf(__int_as_float(r.y), h[(size_t)r.x * NDIM + lane], acc);
    }
    out[(size_t)n * NDIM + lane] = acc;
}

extern "C" void kernel_launch(void* const* d_in, const int* in_sizes, int n_in,
                              void* d_out, int out_size, void* d_ws, size_t ws_size,
                              hipStream_t stream) {
    const float* h   = (const float*)d_in[0];
    const float* pw  = (const float*)d_in[1];
    const float* nw  = (const float*)d_in[2];
    const int* edges = (const int*)d_in[3];
    float* out = (float*)d_out;

    const int n_nodes = in_sizes[0] / NDIM;
    const int n_edges = in_sizes[3] / 8;
    const size_t E = (size_t)n_edges, N = (size_t)n_nodes;

    const size_t szPv = E * 4, szRec = E * 4;
    const size_t szH16 = N * NDIM * 2, szG16 = N * NDIM * 2, szS12 = N * 8;
    const size_t szOffs = (N + 1) * 4, szDen = N * 4, szB = 16384;
    const size_t need_A = szPv + szRec + szH16 + szG16 + szS12 + szOffs + szDen + szB;
    const bool tierA = (ws_size >= need_A) && (n_nodes <= 65536);

    const int eb  = (n_edges + 255) / 256;
    const int nbN = (n_nodes + 255) / 256;
    const int nw4 = (n_nodes + 3) / 4;

    if (tierA) {
        char* p = (char*)d_ws;
        unsigned* pvivj = (unsigned*)p;           p += szPv;
        unsigned* rec   = (unsigned*)p;           p += szRec;
        unsigned short* h16 = (unsigned short*)p; p += szH16;
        unsigned short* g16 = (unsigned short*)p; p += szG16;
        float2* s12   = (float2*)p;               p += szS12;
        int*    offs  = (int*)p;                  p += szOffs;   // hist -> offsets -> cursors
        float*  denom = (float*)p;                p += szDen;
        int*    bsum  = (int*)p;                  p += szB;

        hipMemsetAsync(offs, 0, szOffs + szDen, stream);   // offs + denom contiguous

        k_prep_pack<<<nw4 + eb, 256, 0, stream>>>(h, pw, nw, h16, s12,
                                                  edges, pvivj, offs,
                                                  n_nodes, n_edges, nw4);
        scan_blocks<<<nbN, 256, 0, stream>>>(offs, bsum, n_nodes);
        scan_top<<<1, 256, 0, stream>>>(bsum, nbN);
        scan_add<<<(n_nodes + 1 + 255) / 256, 256, 0, stream>>>(offs, bsum, n_nodes, n_edges);

        const int npairs = (n_edges + 1) / 2;
        k1_fused2<<<(npairs + 255) / 256, 256, 0, stream>>>(pvivj, h16, s12,
                                                            pw + 128, nw + 128,
                                                            denom, offs, rec, n_edges);
        k_gmul<<<nw4, 256, 0, stream>>>(h16, denom, g16, n_nodes);
        k3b_gather<<<nw4, 256, 0, stream>>>(rec, offs, g16, out, n_nodes);
    } else {
        char* p = (char*)d_ws;
        float* ex    = (float*)p;  p += E * 4;
        int2*  rec8  = (int2*)p;   p += E * 8;
        int*   offs  = (int*)p;    p += (N + 1) * 4;
        float* rdenom = (float*)p; p += N * 4;
        int*   bsum  = (int*)p;    p += 16384;

        hipMemsetAsync(offs, 0, (N + 1) * 4, stream);
        k1_full_c<<<eb, 256, 0, stream>>>(edges, h, pw, nw, ex, offs, n_edges);
        scan_blocks<<<nbN, 256, 0, stream>>>(offs, bsum, n_nodes);
        scan_top<<<1, 256, 0, stream>>>(bsum, nbN);
        scan_add<<<(n_nodes + 1 + 255) / 256, 256, 0, stream>>>(offs, bsum, n_nodes, n_edges);
        k2_denom_c<<<nbN, 256, 0, stream>>>(edges, ex, rdenom, n_edges, n_nodes);
        k3a_scatter_c<<<eb, 256, 0, stream>>>(edges, ex, rdenom, offs, rec8, n_edges);
        k3b_gather_c<<<nw4, 256, 0, stream>>>(rec8, offs, h, out, n_nodes);
    }
}

// Round 15
// 240.880 us; speedup vs baseline: 1.0913x; 1.0913x over previous
//
#include <hip/hip_runtime.h>
#include <math.h>

#define NDIM 64

__device__ __forceinline__ unsigned bf16rne(unsigned u) {
    return (u + 0x7fffu + ((u >> 16) & 1u)) >> 16;
}

// ---------- fused nodeprep + pack ----------
__global__ void __launch_bounds__(256)
k_prep_pack(const float* __restrict__ h,
            const float* __restrict__ pw, const float* __restrict__ nw,
            unsigned short* __restrict__ h16, float2* __restrict__ s12,
            const int* __restrict__ edges, unsigned* __restrict__ pvivj,
            int* __restrict__ hist,
            int n_nodes, int n_edges, int node_blocks) {
    if ((int)blockIdx.x < node_blocks) {
        const int lane = threadIdx.x & 63;
        const int n = blockIdx.x * 4 + (threadIdx.x >> 6);
        if (n >= n_nodes) return;
        const float a = h[(size_t)n * NDIM + lane];
        const float pa = fmaxf(a, 0.f), na = pa - a;
        float t1 = pa * pw[lane]      - na * nw[lane];
        float t2 = pa * pw[64 + lane] - na * nw[64 + lane];
        #pragma unroll
        for (int m = 32; m >= 1; m >>= 1) {
            t1 += __shfl_xor(t1, m, 64);
            t2 += __shfl_xor(t2, m, 64);
        }
        h16[(size_t)n * NDIM + lane] = (unsigned short)bf16rne(__float_as_uint(a));
        if (lane == 0) s12[n] = make_float2(t1, t2);
    } else {
        const int e = ((int)blockIdx.x - node_blocks) * 256 + threadIdx.x;
        if (e >= n_edges) return;
        const int vi = __builtin_nontemporal_load(edges + (size_t)e * 8 + 1);
        const int vj = __builtin_nontemporal_load(edges + (size_t)e * 8 + 2);
        __builtin_nontemporal_store((unsigned)vi | ((unsigned)vj << 16), pvivj + e);
        atomicAdd(&hist[vj], 1);   // vj random -> low contention
    }
}

// ---------- 3-level exclusive scan ----------
__global__ void __launch_bounds__(256)
scan_blocks(int* __restrict__ data, int* __restrict__ bsum, int n) {
    __shared__ int sm[256];
    const int t = threadIdx.x;
    const int i = blockIdx.x * 256 + t;
    int v = (i < n) ? data[i] : 0;
    sm[t] = v;
    __syncthreads();
    int x = v;
    #pragma unroll
    for (int off = 1; off < 256; off <<= 1) {
        int add = (t >= off) ? sm[t - off] : 0;
        __syncthreads();
        x += add; sm[t] = x;
        __syncthreads();
    }
    if (i < n) data[i] = x - v;
    if (t == 255) bsum[blockIdx.x] = x;
}

__global__ void __launch_bounds__(256)
scan_top(int* __restrict__ bsum, int nb) {
    __shared__ int sm[256];
    const int t = threadIdx.x;
    const int chunk = (nb + 255) / 256;
    const int beg = t * chunk, end = min(beg + chunk, nb);
    int s = 0;
    for (int i = beg; i < end; ++i) s += bsum[i];
    sm[t] = s;
    __syncthreads();
    int x = s;
    #pragma unroll
    for (int off = 1; off < 256; off <<= 1) {
        int add = (t >= off) ? sm[t - off] : 0;
        __syncthreads();
        x += add; sm[t] = x;
        __syncthreads();
    }
    int run = x - s;
    for (int i = beg; i < end; ++i) { const int v = bsum[i]; bsum[i] = run; run += v; }
}

__global__ void __launch_bounds__(256)
scan_add(int* __restrict__ data, const int* __restrict__ bsum, int n, int total) {
    const int i = blockIdx.x * 256 + threadIdx.x;
    if (i < n) data[i] += bsum[blockIdx.x];
    else if (i == n) data[i] = total;
}

// ---------- k1: TWO consecutive edges per thread; vj rows hoisted; NT rec store ----------
__global__ void __launch_bounds__(256)
k1_fused2(const unsigned* __restrict__ pvivj,
          const unsigned short* __restrict__ h16,
          const float2* __restrict__ s12,
          const float* __restrict__ w2p, const float* __restrict__ w2n,
          float* __restrict__ ex,
          int* __restrict__ offs,           // running cursors (post-scan)
          unsigned* __restrict__ rec,       // (vi<<16) | bf16(ex)
          int n_edges) {
    const int t = blockIdx.x * 256 + threadIdx.x;
    const int e0 = t * 2;
    if (e0 >= n_edges) return;
    const bool has1 = (e0 + 1 < n_edges);

    const unsigned v0 = pvivj[e0];
    const unsigned v1 = has1 ? pvivj[e0 + 1] : v0;
    const int vi0 = (int)(v0 & 0xffffu), vj0 = (int)(v0 >> 16);
    const int vi1 = (int)(v1 & 0xffffu), vj1 = (int)(v1 >> 16);

    const uint4* hj0 = (const uint4*)(h16 + (size_t)vj0 * NDIM);
    const uint4* hj1 = (const uint4*)(h16 + (size_t)vj1 * NDIM);
    const uint4* hi0 = (const uint4*)(h16 + (size_t)vi0 * NDIM);
    const uint4* hi1 = (const uint4*)(h16 + (size_t)vi1 * NDIM);

    // hoist the RANDOM (vj) rows of both edges: 16 independent loads in flight
    uint4 B0[8], B1[8];
    #pragma unroll
    for (int q = 0; q < 8; ++q) { B0[q] = hj0[q]; B1[q] = hj1[q]; }

    float cp0 = 0.f, cn0 = 0.f, cp1 = 0.f, cn1 = 0.f;
    #pragma unroll
    for (int q = 0; q < 8; ++q) {
        const uint4 ua0 = hi0[q];          // vi side: sorted -> L1 hits, load inline
        const uint4 ua1 = hi1[q];
        const unsigned a0u[4] = {ua0.x, ua0.y, ua0.z, ua0.w};
        const unsigned a1u[4] = {ua1.x, ua1.y, ua1.z, ua1.w};
        const unsigned b0u[4] = {B0[q].x, B0[q].y, B0[q].z, B0[q].w};
        const unsigned b1u[4] = {B1[q].x, B1[q].y, B1[q].z, B1[q].w};
        #pragma unroll
        for (int k = 0; k < 4; ++k) {
            const int d = q * 8 + k * 2;
            const float w2pd = w2p[d], w2pd1 = w2p[d + 1];
            const float w2nd = w2n[d], w2nd1 = w2n[d + 1];
            {
                const float a0 = __uint_as_float(a0u[k] << 16);
                const float a1 = __uint_as_float(a0u[k] & 0xffff0000u);
                const float b0 = __uint_as_float(b0u[k] << 16);
                const float b1 = __uint_as_float(b0u[k] & 0xffff0000u);
                const float pa0 = fmaxf(a0, 0.f), na0 = pa0 - a0;
                const float pb0 = fmaxf(b0, 0.f), nb0 = pb0 - b0;
                const float pa1 = fmaxf(a1, 0.f), na1 = pa1 - a1;
                const float pb1 = fmaxf(b1, 0.f), nb1 = pb1 - b1;
                cp0 = fmaf(pa0 * pb0, w2pd,  cp0);
                cn0 = fmaf(na0 * nb0, w2nd,  cn0);
                cp0 = fmaf(pa1 * pb1, w2pd1, cp0);
                cn0 = fmaf(na1 * nb1, w2nd1, cn0);
            }
            {
                const float a0 = __uint_as_float(a1u[k] << 16);
                const float a1 = __uint_as_float(a1u[k] & 0xffff0000u);
                const float b0 = __uint_as_float(b1u[k] << 16);
                const float b1 = __uint_as_float(b1u[k] & 0xffff0000u);
                const float pa0 = fmaxf(a0, 0.f), na0 = pa0 - a0;
                const float pb0 = fmaxf(b0, 0.f), nb0 = pb0 - b0;
                const float pa1 = fmaxf(a1, 0.f), na1 = pa1 - a1;
                const float pb1 = fmaxf(b1, 0.f), nb1 = pb1 - b1;
                cp1 = fmaf(pa0 * pb0, w2pd,  cp1);
                cn1 = fmaf(na0 * nb0, w2nd,  cn1);
                cp1 = fmaf(pa1 * pb1, w2pd1, cp1);
                cn1 = fmaf(na1 * nb1, w2nd1, cn1);
            }
        }
    }
    const float2 si0 = s12[vi0], sj0 = s12[vj0];
    const float2 si1 = s12[vi1], sj1 = s12[vj1];
    const float exf0 = __expf(si0.x + sj0.y + cp0 - cn0);
    const float exf1 = __expf(si1.x + sj1.y + cp1 - cn1);

    __builtin_nontemporal_store(exf0, ex + e0);
    const int pos0 = atomicAdd(&offs[vj0], 1);
    __builtin_nontemporal_store(((unsigned)vi0 << 16) | bf16rne(__float_as_uint(exf0)), rec + pos0);
    if (has1) {
        __builtin_nontemporal_store(exf1, ex + e0 + 1);
        const int pos1 = atomicAdd(&offs[vj1], 1);
        __builtin_nontemporal_store(((unsigned)vi1 << 16) | bf16rne(__float_as_uint(exf1)), rec + pos1);
    }
}

// ---------- k2: wave-segmented sum of ex over sorted-vi runs -> denom ----------
__global__ void __launch_bounds__(256)
k2_seg(const unsigned* __restrict__ pvivj, const float* __restrict__ ex,
       float* __restrict__ denom, int n_edges) {
    const int e = blockIdx.x * 256 + threadIdx.x;
    const int lane = threadIdx.x & 63;
    const bool valid = (e < n_edges);
    const int vi = valid ? (int)(pvivj[e] & 0xffffu) : -1;
    float s = valid ? ex[e] : 0.f;
    #pragma unroll
    for (int o = 1; o < 64; o <<= 1) {
        const float pv = __shfl_up(s, o, 64);
        const int   pi = __shfl_up(vi, o, 64);
        if (lane >= o && pi == vi) s += pv;
    }
    const int nvi = __shfl_down(vi, 1, 64);
    if ((lane == 63 || nvi != vi) && vi >= 0)
        atomicAdd(&denom[vi], s);     // ~2 adds per vi, spread
}

// ---------- gmul: g16 = bf16(h16 / denom) ----------
__global__ void __launch_bounds__(256)
k_gmul(const unsigned short* __restrict__ h16, const float* __restrict__ denom,
       unsigned short* __restrict__ g16, int n_nodes) {
    const int lane = threadIdx.x & 63;
    const int n = blockIdx.x * 4 + (threadIdx.x >> 6);
    if (n >= n_nodes) return;
    const float d = denom[n];
    const float r = (d > 0.f) ? 1.f / d : 0.f;
    const float hv = __uint_as_float((unsigned)h16[(size_t)n * NDIM + lane] << 16);
    g16[(size_t)n * NDIM + lane] = (unsigned short)bf16rne(__float_as_uint(hv * r));
}

// ---------- gather: wave per node, single segment, x16 unroll ----------
__global__ void __launch_bounds__(256)
k3b_gather(const unsigned* __restrict__ rec, const int* __restrict__ offs,
           const unsigned short* __restrict__ g16,
           float* __restrict__ out, int n_nodes) {
    const int lane = threadIdx.x & 63;
    const int n = blockIdx.x * 4 + (threadIdx.x >> 6);
    if (n >= n_nodes) return;
    const int beg = (n == 0) ? 0 : offs[n - 1];
    const int end = offs[n];
    float acc = 0.f;
    int k = beg;
    for (; k + 16 <= end; k += 16) {
        unsigned r[16];
        #pragma unroll
        for (int u = 0; u < 16; ++u) r[u] = __builtin_nontemporal_load(rec + k + u);
        float v[16];
        #pragma unroll
        for (int u = 0; u < 16; ++u)
            v[u] = __uint_as_float((unsigned)g16[(size_t)(r[u] >> 16) * NDIM + lane] << 16);
        #pragma unroll
        for (int u = 0; u < 16; ++u)
            acc = fmaf(__uint_as_float(r[u] << 16), v[u], acc);
    }
    for (; k + 4 <= end; k += 4) {
        unsigned r[4];
        #pragma unroll
        for (int u = 0; u < 4; ++u) r[u] = __builtin_nontemporal_load(rec + k + u);
        #pragma unroll
        for (int u = 0; u < 4; ++u)
            acc = fmaf(__uint_as_float(r[u] << 16),
                       __uint_as_float((unsigned)g16[(size_t)(r[u] >> 16) * NDIM + lane] << 16), acc);
    }
    for (; k < end; ++k) {
        const unsigned r = __builtin_nontemporal_load(rec + k);
        acc = fmaf(__uint_as_float(r << 16),
                   __uint_as_float((unsigned)g16[(size_t)(r >> 16) * NDIM + lane] << 16), acc);
    }
    __builtin_nontemporal_store(acc, out + (size_t)n * NDIM + lane);
}

// ================= tier C fallback (small ws; fp32, proven kernels) =================
__device__ __forceinline__ float edge_term(float a, float b,
                                           float w0, float w1, float w2,
                                           float w3, float w4, float w5) {
    const float pa = fmaxf(a, 0.f), na = pa - a;
    const float pb = fmaxf(b, 0.f), nb = pb - b;
    return pa * w0 + pb * w1 + (pa * pb) * w2
         - (na * w3 + nb * w4 + (na * nb) * w5);
}

__global__ void __launch_bounds__(256)
k1_full_c(const int* __restrict__ edges, const float* __restrict__ h,
          const float* __restrict__ pw, const float* __restrict__ nw,
          float* __restrict__ ex, int* __restrict__ hist, int n_edges) {
    const int e = blockIdx.x * 256 + threadIdx.x;
    if (e >= n_edges) return;
    const int vi = edges[(size_t)e * 8 + 1];
    const int vj = edges[(size_t)e * 8 + 2];
    const float4* hi = (const float4*)(h + (size_t)vi * NDIM);
    const float4* hj = (const float4*)(h + (size_t)vj * NDIM);
    float c = 0.f;
    #pragma unroll 4
    for (int q = 0; q < 16; ++q) {
        const float4 a = hi[q];
        const float4 b = hj[q];
        const int d = q * 4;
        c += edge_term(a.x, b.x, pw[d],     pw[64 + d],     pw[128 + d],
                                 nw[d],     nw[64 + d],     nw[128 + d]);
        c += edge_term(a.y, b.y, pw[d + 1], pw[64 + d + 1], pw[128 + d + 1],
                                 nw[d + 1], nw[64 + d + 1], nw[128 + d + 1]);
        c += edge_term(a.z, b.z, pw[d + 2], pw[64 + d + 2], pw[128 + d + 2],
                                 nw[d + 2], nw[64 + d + 2], nw[128 + d + 2]);
        c += edge_term(a.w, b.w, pw[d + 3], pw[64 + d + 3], pw[128 + d + 3],
                                 nw[d + 3], nw[64 + d + 3], nw[128 + d + 3]);
    }
    ex[e] = __expf(c);
    atomicAdd(&hist[vj], 1);
}

__global__ void __launch_bounds__(256)
k2_denom_c(const int* __restrict__ edges, const float* __restrict__ ex,
           float* __restrict__ rdenom, int n_edges, int n_nodes) {
    const int n = blockIdx.x * 256 + threadIdx.x;
    if (n >= n_nodes) return;
    int lo = 0, hi = n_edges;
    while (lo < hi) { int mid = (lo + hi) >> 1; if (edges[(size_t)mid * 8 + 1] < n) lo = mid + 1; else hi = mid; }
    const int beg = lo;
    hi = n_edges;
    while (lo < hi) { int mid = (lo + hi) >> 1; if (edges[(size_t)mid * 8 + 1] < n + 1) lo = mid + 1; else hi = mid; }
    const int end = lo;
    float s = 0.f;
    for (int e = beg; e < end; ++e) s += ex[e];
    rdenom[n] = (end > beg) ? 1.f / s : 0.f;
}

__global__ void __launch_bounds__(256)
k3a_scatter_c(const int* __restrict__ edges, const float* __restrict__ ex,
              const float* __restrict__ rdenom,
              int* __restrict__ offs, int2* __restrict__ rec8, int n_edges) {
    const int e = blockIdx.x * 256 + threadIdx.x;
    if (e >= n_edges) return;
    const int vi = edges[(size_t)e * 8 + 1];
    const int vj = edges[(size_t)e * 8 + 2];
    const float attn = ex[e] * rdenom[vi];
    const int pos = atomicAdd(&offs[vj], 1);
    rec8[pos] = make_int2(vi, __float_as_int(attn));
}

__global__ void __launch_bounds__(256)
k3b_gather_c(const int2* __restrict__ rec8, const int* __restrict__ offs,
             const float* __restrict__ h, float* __restrict__ out, int n_nodes) {
    const int lane = threadIdx.x & 63;
    const int n = blockIdx.x * 4 + (threadIdx.x >> 6);
    if (n >= n_nodes) return;
    const int beg = (n == 0) ? 0 : offs[n - 1];
    const int end = offs[n];
    float acc = 0.f;
    for (int k = beg; k < end; ++k) {
        const int2 r = rec8[k];
        acc = fmaf(__int_as_float(r.y), h[(size_t)r.x * NDIM + lane], acc);
    }
    out[(size_t)n * NDIM + lane] = acc;
}

extern "C" void kernel_launch(void* const* d_in, const int* in_sizes, int n_in,
                              void* d_out, int out_size, void* d_ws, size_t ws_size,
                              hipStream_t stream) {
    const float* h   = (const float*)d_in[0];
    const float* pw  = (const float*)d_in[1];
    const float* nw  = (const float*)d_in[2];
    const int* edges = (const int*)d_in[3];
    float* out = (float*)d_out;

    const int n_nodes = in_sizes[0] / NDIM;
    const int n_edges = in_sizes[3] / 8;
    const size_t E = (size_t)n_edges, N = (size_t)n_nodes;

    const size_t szPv = E * 4, szRec = E * 4, szEx = E * 4;
    const size_t szH16 = N * NDIM * 2, szG16 = N * NDIM * 2, szS12 = N * 8;
    const size_t szOffs = (N + 1) * 4, szDen = N * 4, szB = 16384;
    const size_t need_A = szPv + szRec + szEx + szH16 + szG16 + szS12 + szOffs + szDen + szB;
    const bool tierA = (ws_size >= need_A) && (n_nodes <= 65536);

    const int eb  = (n_edges + 255) / 256;
    const int nbN = (n_nodes + 255) / 256;
    const int nw4 = (n_nodes + 3) / 4;

    if (tierA) {
        char* p = (char*)d_ws;
        unsigned* pvivj = (unsigned*)p;           p += szPv;
        unsigned* rec   = (unsigned*)p;           p += szRec;
        float*    ex    = (float*)p;              p += szEx;
        unsigned short* h16 = (unsigned short*)p; p += szH16;
        unsigned short* g16 = (unsigned short*)p; p += szG16;
        float2* s12   = (float2*)p;               p += szS12;
        int*    offs  = (int*)p;                  p += szOffs;   // hist -> offsets -> cursors
        float*  denom = (float*)p;                p += szDen;
        int*    bsum  = (int*)p;                  p += szB;

        hipMemsetAsync(offs, 0, szOffs + szDen, stream);   // offs + denom contiguous

        k_prep_pack<<<nw4 + eb, 256, 0, stream>>>(h, pw, nw, h16, s12,
                                                  edges, pvivj, offs,
                                                  n_nodes, n_edges, nw4);
        scan_blocks<<<nbN, 256, 0, stream>>>(offs, bsum, n_nodes);
        scan_top<<<1, 256, 0, stream>>>(bsum, nbN);
        scan_add<<<(n_nodes + 1 + 255) / 256, 256, 0, stream>>>(offs, bsum, n_nodes, n_edges);

        const int npairs = (n_edges + 1) / 2;
        k1_fused2<<<(npairs + 255) / 256, 256, 0, stream>>>(pvivj, h16, s12,
                                                            pw + 128, nw + 128,
                                                            ex, offs, rec, n_edges);
        k2_seg<<<eb, 256, 0, stream>>>(pvivj, ex, denom, n_edges);
        k_gmul<<<nw4, 256, 0, stream>>>(h16, denom, g16, n_nodes);
        k3b_gather<<<nw4, 256, 0, stream>>>(rec, offs, g16, out, n_nodes);
    } else {
        char* p = (char*)d_ws;
        float* ex    = (float*)p;  p += E * 4;
        int2*  rec8  = (int2*)p;   p += E * 8;
        int*   offs  = (int*)p;    p += (N + 1) * 4;
        float* rdenom = (float*)p; p += N * 4;
        int*   bsum  = (int*)p;    p += 16384;

        hipMemsetAsync(offs, 0, (N + 1) * 4, stream);
        k1_full_c<<<eb, 256, 0, stream>>>(edges, h, pw, nw, ex, offs, n_edges);
        scan_blocks<<<nbN, 256, 0, stream>>>(offs, bsum, n_nodes);
        scan_top<<<1, 256, 0, stream>>>(bsum, nbN);
        scan_add<<<(n_nodes + 1 + 255) / 256, 256, 0, stream>>>(offs, bsum, n_nodes, n_edges);
        k2_denom_c<<<nbN, 256, 0, stream>>>(edges, ex, rdenom, n_edges, n_nodes);
        k3a_scatter_c<<<eb, 256, 0, stream>>>(edges, ex, rdenom, offs, rec8, n_edges);
        k3b_gather_c<<<nw4, 256, 0, stream>>>(rec8, offs, h, out, n_nodes);
    }
}